// Round 3
// baseline (565.125 us; speedup 1.0000x reference)
//
#include <hip/hip_runtime.h>

// ---------------- problem constants ----------------
#define NG   64            // graphs
#define NPG  4096          // nodes per graph
#define C    256           // channels
#define NTOT (NG * NPG)    // 262144 nodes
#define K    2048          // kept per graph (ceil(0.5*4096))
#define KT   (NG * K)      // 131072 kept total
#define EPG  (NPG * 16)    // 65536 edges per graph
#define ET   (NG * EPG)    // 4194304 edges total

// output layout (floats), concatenated in reference return order
#define OFF_X     0
#define OFF_EI    (KT * C)                 // 33554432
#define OFF_ATTR  (OFF_EI + 2 * ET)        // 41943040
#define OFF_BATCH (OFF_ATTR + ET)          // 46137344
#define OFF_PERM  (OFF_BATCH + KT)         // 46268416
#define OFF_SCORE (OFF_PERM + KT)          // 46399488
#define OFF_MASK  (OFF_SCORE + KT)         // 46530560

// XLA/Eigen FastTanh for f32 (bitwise-matches XLA EmitTanh(F32))
__device__ __forceinline__ float xla_tanh(float x) {
  float ax = fabsf(x);
  if (ax < 0.0004f) return x;
  const float c = 7.90531110763549805f;
  float t = fminf(fmaxf(x, -c), c);
  float x2 = t * t;
  float p = fmaf(x2, -2.76076847742355e-16f, 2.00018790482477e-13f);
  p = fmaf(x2, p, -8.60467152213735e-11f);
  p = fmaf(x2, p, 5.12229709037114e-08f);
  p = fmaf(x2, p, 1.48572235717979e-05f);
  p = fmaf(x2, p, 6.37261928875436e-04f);
  p = fmaf(x2, p, 4.89352455891786e-03f);
  p = t * p;
  float q = fmaf(x2, 1.19825839466702e-06f, 1.18534705686654e-04f);
  q = fmaf(x2, q, 2.26843463243900e-03f);
  q = fmaf(x2, q, 4.89352518554385e-03f);
  return p / q;
}

// ---------------- kernel 1: scores -> sortable keys ----------------
// Arithmetic kept BITWISE IDENTICAL to round 1 (which passed): per-lane
// 4-elem serial FMA, 6-level xor-tree over 64 lanes, xla_tanh(d/sqrt(n)).
// key = (~orderable(score) << 32) | local_idx  -> ascending u64 order ==
// score descending, index ascending on ties (matches jax.lax.top_k).
__global__ __launch_bounds__(256) void score_kernel(
    const float* __restrict__ x, const float* __restrict__ w,
    unsigned long long* __restrict__ keys) {
  int node = (int)((blockIdx.x * blockDim.x + threadIdx.x) >> 6);
  int lane = threadIdx.x & 63;
  const float4 xv = *reinterpret_cast<const float4*>(x + (size_t)node * C + lane * 4);
  const float4 wv = *reinterpret_cast<const float4*>(w + lane * 4);
  float d = xv.x * wv.x;
  d = fmaf(xv.y, wv.y, d);
  d = fmaf(xv.z, wv.z, d);
  d = fmaf(xv.w, wv.w, d);
  float n = wv.x * wv.x;
  n = fmaf(wv.y, wv.y, n);
  n = fmaf(wv.z, wv.z, n);
  n = fmaf(wv.w, wv.w, n);
  #pragma unroll
  for (int off = 1; off < 64; off <<= 1) {
    d += __shfl_xor(d, off);
    n += __shfl_xor(n, off);
  }
  if (lane == 0) {
    float s = xla_tanh(d / sqrtf(n));
    unsigned int u = __float_as_uint(s);
    u = (u & 0x80000000u) ? ~u : (u | 0x80000000u);  // ascending-orderable
    u = ~u;                                          // descending
    keys[node] = ((unsigned long long)u << 32) | (unsigned int)(node & (NPG - 1));
  }
}

// ---------------- kernel 2: rank-by-counting top-k ----------------
// Keys are unique -> rank(i) = #{j : key[j] < key[i]} reproduces exactly
// the ascending-u64 sorted order (identical perm to a full sort).
// j-loop address is wave-uniform -> scalar loads, L1-resident (32KB/graph).
__global__ __launch_bounds__(512) void topk_kernel(
    const unsigned long long* __restrict__ keys, int* __restrict__ perm_i32,
    int* __restrict__ new_id, float* __restrict__ out) {
  const int g = blockIdx.x >> 3;                       // 8 blocks per graph
  const int i = ((blockIdx.x & 7) << 9) | threadIdx.x; // 0..4095
  const unsigned long long* kb = keys + g * NPG;
  const unsigned long long my = kb[i];

  int r0 = 0, r1 = 0, r2 = 0, r3 = 0;
  #pragma unroll 4
  for (int j = 0; j < NPG; j += 4) {
    r0 += (kb[j]     < my);
    r1 += (kb[j + 1] < my);
    r2 += (kb[j + 2] < my);
    r3 += (kb[j + 3] < my);
  }
  int rank = (r0 + r1) + (r2 + r3);

  int node = g * NPG + i;
  if (rank < K) {
    int nid = g * K + rank;
    new_id[node] = nid;
    perm_i32[nid] = node;
    // reconstruct exact score bits from key high word
    unsigned int t = ~(unsigned int)(my >> 32);
    unsigned int su = (t & 0x80000000u) ? (t ^ 0x80000000u) : ~t;
    out[OFF_BATCH + nid] = (float)g;
    out[OFF_PERM + nid]  = (float)node;
    out[OFF_SCORE + nid] = __uint_as_float(su);
  } else {
    new_id[node] = -1;
  }
}

// ---------------- kernel 3: fused edge-filter + x gather ----------------
// Edge blocks first (latency-bound new_id gathers) so they overlap with the
// BW-bound row copies that follow in dispatch order.
#define EBLOCKS (ET / 4 / 256)   // 4096
#define GBLOCKS (KT / 4)         // 32768
__global__ __launch_bounds__(256) void tail_kernel(
    const float* __restrict__ x, const int* __restrict__ ei,
    const float* __restrict__ attr, const int* __restrict__ perm_i32,
    const int* __restrict__ new_id, float* __restrict__ out) {
  int b = blockIdx.x;
  if (b < EBLOCKS) {
    int t = b * 256 + threadIdx.x;           // edge quad id
    int4 r = reinterpret_cast<const int4*>(ei)[t];
    int4 c = reinterpret_cast<const int4*>(ei + ET)[t];
    float4 a = reinterpret_cast<const float4*>(attr)[t];
    int nr[4] = {new_id[r.x], new_id[r.y], new_id[r.z], new_id[r.w]};
    int nc[4] = {new_id[c.x], new_id[c.y], new_id[c.z], new_id[c.w]};
    float4 e0, e1, ao, mo;
    float* e0p = &e0.x; float* e1p = &e1.x; float* aop = &ao.x; float* mop = &mo.x;
    const float* ap = &a.x;
    #pragma unroll
    for (int q = 0; q < 4; ++q) {
      bool keep = (nr[q] >= 0) && (nc[q] >= 0);
      e0p[q] = keep ? (float)nr[q] : -1.0f;
      e1p[q] = keep ? (float)nc[q] : -1.0f;
      aop[q] = keep ? ap[q] : 0.0f;
      mop[q] = keep ? 1.0f : 0.0f;
    }
    reinterpret_cast<float4*>(out + OFF_EI)[t]      = e0;
    reinterpret_cast<float4*>(out + OFF_EI + ET)[t] = e1;
    reinterpret_cast<float4*>(out + OFF_ATTR)[t]    = ao;
    reinterpret_cast<float4*>(out + OFF_MASK)[t]    = mo;
  } else {
    int bb = b - EBLOCKS;
    int row = bb * 4 + (threadIdx.x >> 6);
    int lane = threadIdx.x & 63;
    int node = perm_i32[row];
    *reinterpret_cast<float4*>(out + OFF_X + (size_t)row * C + lane * 4) =
        *reinterpret_cast<const float4*>(x + (size_t)node * C + lane * 4);
  }
}

// ---------------- launch ----------------
extern "C" void kernel_launch(void* const* d_in, const int* in_sizes, int n_in,
                              void* d_out, int out_size, void* d_ws, size_t ws_size,
                              hipStream_t stream) {
  const float* x    = (const float*)d_in[0];
  const int*   ei   = (const int*)d_in[1];
  const float* attr = (const float*)d_in[2];
  // d_in[3] = batch (unused; derivable)
  const float* w    = (const float*)d_in[4];
  float* out = (float*)d_out;

  unsigned long long* keys = (unsigned long long*)d_ws;          // NTOT u64 (2MB)
  int* perm_i32 = (int*)d_ws + 2 * NTOT;                         // KT ints
  int* new_id   = (int*)d_ws + 2 * NTOT + KT;                    // NTOT ints

  score_kernel<<<dim3(NTOT / 4), dim3(256), 0, stream>>>(x, w, keys);
  topk_kernel<<<dim3(NG * 8), dim3(512), 0, stream>>>(keys, perm_i32, new_id, out);
  tail_kernel<<<dim3(EBLOCKS + GBLOCKS), dim3(256), 0, stream>>>(
      x, ei, attr, perm_i32, new_id, out);
}